// Round 3
// baseline (149.324 us; speedup 1.0000x reference)
//
#include <hip/hip_runtime.h>

// FocalBCELoss: loss = -mean( t*log(p)*(1-p)^2*alpha[c] + (1-t)*log(1-p)*p^2 )
// N=262144, C=64, GAMMA=2.  t in {0,1} exactly =>
//   term = log(q)*w,  q = t?p:(1-p),  w = t?(1-p)^2*a : p^2   (one v_log_f32/elem)
//
// R3: persistent co-resident grid — 2048 blocks x 256 thr = 32 waves/CU on all
// 256 CUs simultaneously (launch_bounds(256,8) caps VGPR<=64). Each thread
// streams 8 float4-pairs with a 2-deep register double-buffer so the two read
// streams never drain to vmcnt(0) between tiles.

constexpr int N_ELEM = 262144 * 64;       // 16,777,216
constexpr int N_VEC4 = N_ELEM / 4;        // 4,194,304 float4s
constexpr int BLOCK  = 256;
constexpr int GRID1  = 2048;              // 8 blocks/CU, fully co-resident
constexpr int STRIDE = GRID1 * BLOCK;     // 524,288 float4s (== 0 mod 64 elems)
constexpr int ITERS  = N_VEC4 / STRIDE;   // 8 float4s per thread per array
constexpr int UNROLL = 2;                 // pipeline group size
constexpr int GROUPS = ITERS / UNROLL;    // 4

__device__ __forceinline__ float focal_term(float p, float t, float a) {
    float u  = 1.0f - p;
    float d  = p - u;                       // 2p-1
    float q  = fmaf(t, d, u);               // t? p : 1-p   (exact: t in {0,1})
    float lg = __logf(q);                   // single fast log
    float wa = u * u * a;                   // t=1 weight
    float pp = p * p;                       // t=0 weight
    float w  = fmaf(t, wa - pp, pp);        // t? wa : pp
    return lg * w;
}

__global__ __launch_bounds__(BLOCK, 8) void focal_partial_kernel(
        const float4* __restrict__ p4,
        const float4* __restrict__ t4,
        const float*  __restrict__ alpha,
        float* __restrict__ partials) {
    const int tid = blockIdx.x * BLOCK + threadIdx.x;

    // STRIDE*4 and blockDim tile are both ==0 mod C: each thread's 4 channels
    // are fixed for the whole kernel -> alpha in registers, no LDS.
    const int c0 = (threadIdx.x * 4) & 63;
    const float a0 = alpha[c0 + 0];
    const float a1 = alpha[c0 + 1];
    const float a2 = alpha[c0 + 2];
    const float a3 = alpha[c0 + 3];

    float4 P[2][UNROLL], T[2][UNROLL];
#pragma unroll
    for (int j = 0; j < UNROLL; ++j) {
        P[0][j] = p4[tid + j * STRIDE];
        T[0][j] = t4[tid + j * STRIDE];
    }

    float acc0 = 0.0f, acc1 = 0.0f;
#pragma unroll
    for (int g = 0; g < GROUPS; ++g) {
        const int cur = g & 1, nxt = cur ^ 1;
        if (g + 1 < GROUPS) {
#pragma unroll
            for (int j = 0; j < UNROLL; ++j) {
                P[nxt][j] = p4[tid + ((g + 1) * UNROLL + j) * STRIDE];
                T[nxt][j] = t4[tid + ((g + 1) * UNROLL + j) * STRIDE];
            }
        }
#pragma unroll
        for (int j = 0; j < UNROLL; ++j) {
            acc0 += focal_term(P[cur][j].x, T[cur][j].x, a0);
            acc0 += focal_term(P[cur][j].y, T[cur][j].y, a1);
            acc1 += focal_term(P[cur][j].z, T[cur][j].z, a2);
            acc1 += focal_term(P[cur][j].w, T[cur][j].w, a3);
        }
    }
    float acc = acc0 + acc1;

    // wave64 shuffle reduce
    for (int off = 32; off > 0; off >>= 1)
        acc += __shfl_down(acc, off, 64);

    __shared__ float s_wave[BLOCK / 64];
    const int lane = threadIdx.x & 63;
    const int wid  = threadIdx.x >> 6;
    if (lane == 0) s_wave[wid] = acc;
    __syncthreads();
    if (threadIdx.x == 0)
        partials[blockIdx.x] = s_wave[0] + s_wave[1] + s_wave[2] + s_wave[3];
}

__global__ __launch_bounds__(BLOCK) void focal_final_kernel(
        const float* __restrict__ partials,
        float* __restrict__ out) {
    double acc = 0.0;
    for (int i = threadIdx.x; i < GRID1; i += BLOCK)
        acc += (double)partials[i];

    for (int off = 32; off > 0; off >>= 1)
        acc += __shfl_down(acc, off, 64);

    __shared__ double s_wave[BLOCK / 64];
    const int lane = threadIdx.x & 63;
    const int wid  = threadIdx.x >> 6;
    if (lane == 0) s_wave[wid] = acc;
    __syncthreads();
    if (threadIdx.x == 0) {
        double total = s_wave[0] + s_wave[1] + s_wave[2] + s_wave[3];
        out[0] = (float)(-total / (double)N_ELEM);
    }
}

extern "C" void kernel_launch(void* const* d_in, const int* in_sizes, int n_in,
                              void* d_out, int out_size, void* d_ws, size_t ws_size,
                              hipStream_t stream) {
    const float4* p4    = (const float4*)d_in[0];   // inputs  [N,C] fp32
    const float4* t4    = (const float4*)d_in[1];   // targets [N,C] fp32
    const float*  alpha = (const float*)d_in[2];    // alpha   [C]   fp32
    float* out      = (float*)d_out;
    float* partials = (float*)d_ws;                 // GRID1 floats, fully rewritten each call

    focal_partial_kernel<<<GRID1, BLOCK, 0, stream>>>(p4, t4, alpha, partials);
    focal_final_kernel<<<1, BLOCK, 0, stream>>>(partials, out);
}

// Round 4
// 140.998 us; speedup vs baseline: 1.0591x; 1.0591x over previous
//
#include <hip/hip_runtime.h>

// FocalBCELoss: loss = -mean( t*log(p)*(1-p)^2*alpha[c] + (1-t)*log(1-p)*p^2 )
// N=262144, C=64, GAMMA=2.  t in {0,1} exactly =>
//   term = log(q)*w,  q = t?p:(1-p),  w = t?(1-p)^2*a : p^2   (one v_log_f32/elem)
//
// R4: identical persistent structure to R3, but all bulk loads are NONTEMPORAL
// (global_load_dwordx4 nt) — data is touched exactly once, L1 allocation is
// pure overhead and the per-CU L1 miss queue is the suspected ~3 TB/s clamp.

typedef float v4f __attribute__((ext_vector_type(4)));

constexpr int N_ELEM = 262144 * 64;       // 16,777,216
constexpr int N_VEC4 = N_ELEM / 4;        // 4,194,304 float4s
constexpr int BLOCK  = 256;
constexpr int GRID1  = 2048;              // 8 blocks/CU, fully co-resident
constexpr int STRIDE = GRID1 * BLOCK;     // 524,288 float4s (== 0 mod 64 elems)
constexpr int ITERS  = N_VEC4 / STRIDE;   // 8 float4s per thread per array
constexpr int UNROLL = 2;                 // pipeline group size
constexpr int GROUPS = ITERS / UNROLL;    // 4

__device__ __forceinline__ float focal_term(float p, float t, float a) {
    float u  = 1.0f - p;
    float d  = p - u;                       // 2p-1
    float q  = fmaf(t, d, u);               // t? p : 1-p   (exact: t in {0,1})
    float lg = __logf(q);                   // single fast log
    float wa = u * u * a;                   // t=1 weight
    float pp = p * p;                       // t=0 weight
    float w  = fmaf(t, wa - pp, pp);        // t? wa : pp
    return lg * w;
}

__global__ __launch_bounds__(BLOCK, 8) void focal_partial_kernel(
        const v4f* __restrict__ p4,
        const v4f* __restrict__ t4,
        const float*  __restrict__ alpha,
        float* __restrict__ partials) {
    const int tid = blockIdx.x * BLOCK + threadIdx.x;

    // STRIDE*4 and the block tile are both ==0 mod C: each thread's 4 channels
    // are fixed for the whole kernel -> alpha in registers, no LDS.
    const int c0 = (threadIdx.x * 4) & 63;
    const float a0 = alpha[c0 + 0];
    const float a1 = alpha[c0 + 1];
    const float a2 = alpha[c0 + 2];
    const float a3 = alpha[c0 + 3];

    v4f P[2][UNROLL], T[2][UNROLL];
#pragma unroll
    for (int j = 0; j < UNROLL; ++j) {
        P[0][j] = __builtin_nontemporal_load(&p4[tid + j * STRIDE]);
        T[0][j] = __builtin_nontemporal_load(&t4[tid + j * STRIDE]);
    }

    float acc0 = 0.0f, acc1 = 0.0f;
#pragma unroll
    for (int g = 0; g < GROUPS; ++g) {
        const int cur = g & 1, nxt = cur ^ 1;
        if (g + 1 < GROUPS) {
#pragma unroll
            for (int j = 0; j < UNROLL; ++j) {
                P[nxt][j] = __builtin_nontemporal_load(&p4[tid + ((g + 1) * UNROLL + j) * STRIDE]);
                T[nxt][j] = __builtin_nontemporal_load(&t4[tid + ((g + 1) * UNROLL + j) * STRIDE]);
            }
        }
#pragma unroll
        for (int j = 0; j < UNROLL; ++j) {
            acc0 += focal_term(P[cur][j].x, T[cur][j].x, a0);
            acc0 += focal_term(P[cur][j].y, T[cur][j].y, a1);
            acc1 += focal_term(P[cur][j].z, T[cur][j].z, a2);
            acc1 += focal_term(P[cur][j].w, T[cur][j].w, a3);
        }
    }
    float acc = acc0 + acc1;

    // wave64 shuffle reduce
    for (int off = 32; off > 0; off >>= 1)
        acc += __shfl_down(acc, off, 64);

    __shared__ float s_wave[BLOCK / 64];
    const int lane = threadIdx.x & 63;
    const int wid  = threadIdx.x >> 6;
    if (lane == 0) s_wave[wid] = acc;
    __syncthreads();
    if (threadIdx.x == 0)
        partials[blockIdx.x] = s_wave[0] + s_wave[1] + s_wave[2] + s_wave[3];
}

__global__ __launch_bounds__(BLOCK) void focal_final_kernel(
        const float* __restrict__ partials,
        float* __restrict__ out) {
    double acc = 0.0;
    for (int i = threadIdx.x; i < GRID1; i += BLOCK)
        acc += (double)partials[i];

    for (int off = 32; off > 0; off >>= 1)
        acc += __shfl_down(acc, off, 64);

    __shared__ double s_wave[BLOCK / 64];
    const int lane = threadIdx.x & 63;
    const int wid  = threadIdx.x >> 6;
    if (lane == 0) s_wave[wid] = acc;
    __syncthreads();
    if (threadIdx.x == 0) {
        double total = s_wave[0] + s_wave[1] + s_wave[2] + s_wave[3];
        out[0] = (float)(-total / (double)N_ELEM);
    }
}

extern "C" void kernel_launch(void* const* d_in, const int* in_sizes, int n_in,
                              void* d_out, int out_size, void* d_ws, size_t ws_size,
                              hipStream_t stream) {
    const v4f*  p4    = (const v4f*)d_in[0];    // inputs  [N,C] fp32
    const v4f*  t4    = (const v4f*)d_in[1];    // targets [N,C] fp32
    const float* alpha = (const float*)d_in[2]; // alpha   [C]   fp32
    float* out      = (float*)d_out;
    float* partials = (float*)d_ws;             // GRID1 floats, fully rewritten each call

    focal_partial_kernel<<<GRID1, BLOCK, 0, stream>>>(p4, t4, alpha, partials);
    focal_final_kernel<<<1, BLOCK, 0, stream>>>(partials, out);
}